// Round 1
// baseline (2467.383 us; speedup 1.0000x reference)
//
#include <hip/hip_runtime.h>

// Problem constants
// z: (64, 256, 32, 32) fp32 ; emb: (1024, 256) fp32
// rows M = 64*32*32 = 65536 pixels, D = 256, K = 1024 codes
// out: [z_q (16777216 fl)] [indices as float (65536)] [vq_loss (1)]
#define OUT_IDX_OFF 16777216
#define OUT_LOSS_OFF 16842752

// ---------------------------------------------------------------------------
// Kernel 0: transpose emb -> ET[d][k] and c[k] = sum_d emb[k][d]^2
// ---------------------------------------------------------------------------
__global__ __launch_bounds__(256) void k_prep(const float* __restrict__ emb,
                                              float* __restrict__ ET,
                                              float* __restrict__ cws) {
  const int k = blockIdx.x;
  const int d = threadIdx.x;
  const float v = emb[k * 256 + d];
  ET[d * 1024 + k] = v;
  __shared__ float red[256];
  red[d] = v * v;
  __syncthreads();
  for (int s = 128; s > 0; s >>= 1) {
    if (d < s) red[d] += red[d + s];
    __syncthreads();
  }
  if (d == 0) cws[k] = red[0];
}

// ---------------------------------------------------------------------------
// Kernel 1: a[r] = ||x_r||^2 replicating numpy pairwise summation exactly:
//   256 elems -> split 128+128; each 128: 8 sequential accumulators stride 8,
//   combine ((r0+r1)+(r2+r3))+((r4+r5)+(r6+r7)); total = s0 + s1.
// ---------------------------------------------------------------------------
__global__ __launch_bounds__(256) void k_a(const float* __restrict__ z,
                                           float* __restrict__ aws) {
#pragma clang fp contract(off)
  const int t = threadIdx.x;
  const int r = (blockIdx.x << 7) + (t & 127);  // row
  const int h = t >> 7;                         // which 128-half of d
  const int n = r >> 10;
  const int hw = r & 1023;
  const float* zp = z + (size_t)n * 262144 + hw + (size_t)h * 131072;
  float acc[8];
#pragma unroll
  for (int j = 0; j < 8; ++j) {
    const float x = zp[(size_t)j * 1024];
    acc[j] = x * x;
  }
  for (int g = 1; g < 16; ++g) {
#pragma unroll
    for (int j = 0; j < 8; ++j) {
      const float x = zp[(size_t)(g * 8 + j) * 1024];
      const float p = x * x;
      acc[j] = acc[j] + p;
    }
  }
  const float s = ((acc[0] + acc[1]) + (acc[2] + acc[3])) +
                  ((acc[4] + acc[5]) + (acc[6] + acc[7]));
  __shared__ float red[256];
  red[t] = s;
  __syncthreads();
  if (t < 128) aws[(blockIdx.x << 7) + t] = red[t] + red[t + 128];
}

// ---------------------------------------------------------------------------
// Kernel 2: GEMM-argmin. Block = 128 rows x all 1024 codes (8 k-tiles of 128).
// 256 threads (16x16), 8x8 microtile split 4+4 for conflict-free ds_read_b128.
// Epilogue replicates numpy's fp32 rounding: s = fl(a - 2*dot) ; s = fl(s + c).
// Strict < with ascending k == np.argmin first-min tie-break.
// ---------------------------------------------------------------------------
__global__ __launch_bounds__(256, 2) void k_gemm(const float* __restrict__ z,
                                                 const float* __restrict__ ET,
                                                 const float* __restrict__ cws,
                                                 const float* __restrict__ aws,
                                                 int* __restrict__ idxws,
                                                 float* __restrict__ out) {
  __shared__ __align__(16) float Xb[2][2048];  // [16 d][128 r]
  __shared__ __align__(16) float Eb[2][2048];  // [16 d][128 k]
  __shared__ float a_l[128];
  __shared__ __align__(16) float c_l[128];

  const int t = threadIdx.x;
  const int tx = t & 15, ty = t >> 4;
  const int r0 = blockIdx.x << 7;
  const int n = r0 >> 10, hw0 = r0 & 1023;
  const float* zbase = z + (size_t)n * 262144 + hw0;

  if (t < 128) a_l[t] = aws[r0 + t];

  const int dsub = t >> 5;         // 0..7
  const int rq4 = (t & 31) << 2;   // 0..124

  float minv[8];
  int mini[8];
#pragma unroll
  for (int i = 0; i < 8; ++i) {
    minv[i] = 3.4028235e38f;
    mini[i] = 0;
  }

  for (int kt = 0; kt < 8; ++kt) {
    const int kbase = kt << 7;
    float acc[8][8];
#pragma unroll
    for (int i = 0; i < 8; ++i)
#pragma unroll
      for (int j = 0; j < 8; ++j) acc[i][j] = 0.0f;

    if (t < 32) *(float4*)&c_l[t << 2] = *(const float4*)&cws[kbase + (t << 2)];

    // stage chunk 0
    float4 xv0 = *(const float4*)&zbase[(size_t)dsub * 1024 + rq4];
    float4 xv1 = *(const float4*)&zbase[(size_t)(dsub + 8) * 1024 + rq4];
    float4 ev0 = *(const float4*)&ET[(size_t)dsub * 1024 + kbase + rq4];
    float4 ev1 = *(const float4*)&ET[(size_t)(dsub + 8) * 1024 + kbase + rq4];
    *(float4*)&Xb[0][dsub * 128 + rq4] = xv0;
    *(float4*)&Xb[0][(dsub + 8) * 128 + rq4] = xv1;
    *(float4*)&Eb[0][dsub * 128 + rq4] = ev0;
    *(float4*)&Eb[0][(dsub + 8) * 128 + rq4] = ev1;
    __syncthreads();

    int cur = 0;
    for (int ch = 0; ch < 16; ++ch) {
      if (ch < 15) {
        const int dch = (ch + 1) << 4;
        xv0 = *(const float4*)&zbase[(size_t)(dch + dsub) * 1024 + rq4];
        xv1 = *(const float4*)&zbase[(size_t)(dch + dsub + 8) * 1024 + rq4];
        ev0 = *(const float4*)&ET[(size_t)(dch + dsub) * 1024 + kbase + rq4];
        ev1 = *(const float4*)&ET[(size_t)(dch + dsub + 8) * 1024 + kbase + rq4];
      }
      const float* Xc = Xb[cur];
      const float* Ec = Eb[cur];
#pragma unroll
      for (int d = 0; d < 16; ++d) {
        const float4 xa = *(const float4*)&Xc[d * 128 + (ty << 2)];
        const float4 xb = *(const float4*)&Xc[d * 128 + 64 + (ty << 2)];
        const float4 ea = *(const float4*)&Ec[d * 128 + (tx << 2)];
        const float4 eb = *(const float4*)&Ec[d * 128 + 64 + (tx << 2)];
        const float xr[8] = {xa.x, xa.y, xa.z, xa.w, xb.x, xb.y, xb.z, xb.w};
        const float er[8] = {ea.x, ea.y, ea.z, ea.w, eb.x, eb.y, eb.z, eb.w};
#pragma unroll
        for (int i = 0; i < 8; ++i)
#pragma unroll
          for (int j = 0; j < 8; ++j)
            acc[i][j] = fmaf(xr[i], er[j], acc[i][j]);
      }
      if (ch < 15) {
        const int nxt = cur ^ 1;
        *(float4*)&Xb[nxt][dsub * 128 + rq4] = xv0;
        *(float4*)&Xb[nxt][(dsub + 8) * 128 + rq4] = xv1;
        *(float4*)&Eb[nxt][dsub * 128 + rq4] = ev0;
        *(float4*)&Eb[nxt][(dsub + 8) * 128 + rq4] = ev1;
        __syncthreads();
        cur = nxt;
      }
    }

    // epilogue: quantized distance + running argmin (ascending k, strict <)
#pragma unroll
    for (int i = 0; i < 8; ++i) {
      const int rl = (i < 4) ? ((ty << 2) + i) : (64 + (ty << 2) + i - 4);
      const float av = a_l[rl];
#pragma unroll
      for (int j = 0; j < 8; ++j) {
        const int kl = (j < 4) ? ((tx << 2) + j) : (64 + (tx << 2) + j - 4);
        float s = fmaf(-2.0f, acc[i][j], av);  // fl(a - 2*dot), single rounding
        s = s + c_l[kl];                       // fl(s + c)
        if (s < minv[i]) {
          minv[i] = s;
          mini[i] = kbase + kl;
        }
      }
    }
    __syncthreads();
  }

  // cross-thread reduction: 16 tx-threads share each row
  float* rv = Xb[0];
  int* ri = (int*)Eb[0];
#pragma unroll
  for (int i = 0; i < 8; ++i) {
    const int rl = (i < 4) ? ((ty << 2) + i) : (64 + (ty << 2) + i - 4);
    rv[tx * 128 + rl] = minv[i];
    ri[tx * 128 + rl] = mini[i];
  }
  __syncthreads();
  if (t < 128) {
    float bv = rv[t];
    int bi = ri[t];
#pragma unroll
    for (int x = 1; x < 16; ++x) {
      const float v = rv[x * 128 + t];
      const int ii = ri[x * 128 + t];
      if (v < bv || (v == bv && ii < bi)) {
        bv = v;
        bi = ii;
      }
    }
    idxws[r0 + t] = bi;
    out[OUT_IDX_OFF + r0 + t] = (float)bi;
  }
}

// ---------------------------------------------------------------------------
// Kernel 3: z_q gather via LDS transpose (coalesced emb reads + NCHW writes),
// indices already written; accumulate vq_loss = 1.02 * mean((z - z_q)^2).
// ---------------------------------------------------------------------------
__global__ __launch_bounds__(256) void k_out(const float* __restrict__ z,
                                             const float* __restrict__ emb,
                                             const int* __restrict__ idxws,
                                             float* __restrict__ out) {
  __shared__ float zq[32][257];
  __shared__ int sidx[32];
  __shared__ float red[256];
  const int t = threadIdx.x;
  const int p0 = blockIdx.x << 5;
  const int n = p0 >> 10, hw0 = p0 & 1023;
  if (t < 32) sidx[t] = idxws[p0 + t];
  __syncthreads();
#pragma unroll
  for (int it = 0; it < 8; ++it) {
    const int i = t + (it << 8);
    const int p = i >> 6;
    const int q = (i & 63) << 2;
    const float4 v = *(const float4*)&emb[(size_t)sidx[p] * 256 + q];
    zq[p][q] = v.x;
    zq[p][q + 1] = v.y;
    zq[p][q + 2] = v.z;
    zq[p][q + 3] = v.w;
  }
  __syncthreads();
  const int p = t & 31, d0 = t >> 5;
  const float* zb = z + (size_t)n * 262144 + hw0 + p;
  float* ob = out + (size_t)n * 262144 + hw0 + p;
  float lacc = 0.0f;
#pragma unroll
  for (int dd = 0; dd < 32; ++dd) {
    const int d = (dd << 3) + d0;
    const float v = zq[p][d];
    const float zv = zb[(size_t)d * 1024];
    ob[(size_t)d * 1024] = v;
    const float df = zv - v;
    lacc = fmaf(df, df, lacc);
  }
  red[t] = lacc;
  __syncthreads();
  for (int s = 128; s > 0; s >>= 1) {
    if (t < s) red[t] += red[t + s];
    __syncthreads();
  }
  if (t == 0) atomicAdd(&out[OUT_LOSS_OFF], red[0] * (1.02f / 16777216.0f));
}

// ---------------------------------------------------------------------------
extern "C" void kernel_launch(void* const* d_in, const int* in_sizes, int n_in,
                              void* d_out, int out_size, void* d_ws,
                              size_t ws_size, hipStream_t stream) {
  const float* z = (const float*)d_in[0];
  const float* emb = (const float*)d_in[1];
  float* out = (float*)d_out;

  // workspace layout (floats): ET[262144] | c[1024] | a[65536] | idx[65536]
  float* ET = (float*)d_ws;
  float* cws = ET + 262144;
  float* aws = cws + 1024;
  int* idxws = (int*)(aws + 65536);

  hipMemsetAsync((char*)d_out + (size_t)OUT_LOSS_OFF * 4, 0, 4, stream);

  k_prep<<<dim3(1024), dim3(256), 0, stream>>>(emb, ET, cws);
  k_a<<<dim3(512), dim3(256), 0, stream>>>(z, aws);
  k_gemm<<<dim3(512), dim3(256), 0, stream>>>(z, ET, cws, aws, idxws, out);
  k_out<<<dim3(2048), dim3(256), 0, stream>>>(z, emb, idxws, out);
}

// Round 2
// 707.241 us; speedup vs baseline: 3.4887x; 3.4887x over previous
//
#include <hip/hip_runtime.h>

// Problem constants
// z: (64, 256, 32, 32) fp32 ; emb: (1024, 256) fp32
// rows M = 64*32*32 = 65536 pixels, D = 256, K = 1024 codes
// out: [z_q (16777216 fl)] [indices as float (65536)] [vq_loss (1)]
#define OUT_IDX_OFF 16777216
#define OUT_LOSS_OFF 16842752

// ---------------------------------------------------------------------------
// Kernel 0: transpose emb -> ET[d][k] and c[k] = sum_d emb[k][d]^2
// ---------------------------------------------------------------------------
__global__ __launch_bounds__(256) void k_prep(const float* __restrict__ emb,
                                              float* __restrict__ ET,
                                              float* __restrict__ cws) {
  const int k = blockIdx.x;
  const int d = threadIdx.x;
  const float v = emb[k * 256 + d];
  ET[d * 1024 + k] = v;
  __shared__ float red[256];
  red[d] = v * v;
  __syncthreads();
  for (int s = 128; s > 0; s >>= 1) {
    if (d < s) red[d] += red[d + s];
    __syncthreads();
  }
  if (d == 0) cws[k] = red[0];
}

// ---------------------------------------------------------------------------
// Kernel 1: a[r] = ||x_r||^2 replicating numpy pairwise summation exactly:
//   256 elems -> split 128+128; each 128: 8 sequential accumulators stride 8,
//   combine ((r0+r1)+(r2+r3))+((r4+r5)+(r6+r7)); total = s0 + s1.
// ---------------------------------------------------------------------------
__global__ __launch_bounds__(256) void k_a(const float* __restrict__ z,
                                           float* __restrict__ aws) {
#pragma clang fp contract(off)
  const int t = threadIdx.x;
  const int r = (blockIdx.x << 7) + (t & 127);  // row
  const int h = t >> 7;                         // which 128-half of d
  const int n = r >> 10;
  const int hw = r & 1023;
  const float* zp = z + (size_t)n * 262144 + hw + (size_t)h * 131072;
  float acc[8];
#pragma unroll
  for (int j = 0; j < 8; ++j) {
    const float x = zp[(size_t)j * 1024];
    acc[j] = x * x;
  }
  for (int g = 1; g < 16; ++g) {
#pragma unroll
    for (int j = 0; j < 8; ++j) {
      const float x = zp[(size_t)(g * 8 + j) * 1024];
      const float p = x * x;
      acc[j] = acc[j] + p;
    }
  }
  const float s = ((acc[0] + acc[1]) + (acc[2] + acc[3])) +
                  ((acc[4] + acc[5]) + (acc[6] + acc[7]));
  __shared__ float red[256];
  red[t] = s;
  __syncthreads();
  if (t < 128) aws[(blockIdx.x << 7) + t] = red[t] + red[t + 128];
}

// ---------------------------------------------------------------------------
// Kernel 2: GEMM-argmin. Block = 128 rows x all 1024 codes (8 k-tiles of 128).
// 256 threads (16x16), 8x8 microtile split 4+4 for conflict-free ds_read_b128.
// Epilogue replicates numpy's fp32 rounding: s = fl(a - 2*dot) ; s = fl(s + c).
// Strict < with ascending k == np.argmin first-min tie-break.
// __launch_bounds__(256, 1): round-1's (256,2) capped the VGPR budget at 128
// and spilled acc[8][8] to scratch (7 GB HBM writes, VALUBusy 12%). Budget 512
// lets the ~150-180 live regs stay in the RF.
// ---------------------------------------------------------------------------
__global__ __launch_bounds__(256, 1) void k_gemm(const float* __restrict__ z,
                                                 const float* __restrict__ ET,
                                                 const float* __restrict__ cws,
                                                 const float* __restrict__ aws,
                                                 int* __restrict__ idxws,
                                                 float* __restrict__ out) {
  __shared__ __align__(16) float Xb[2][2048];  // [16 d][128 r]
  __shared__ __align__(16) float Eb[2][2048];  // [16 d][128 k]
  __shared__ float a_l[128];
  __shared__ __align__(16) float c_l[128];

  const int t = threadIdx.x;
  const int tx = t & 15, ty = t >> 4;
  const int r0 = blockIdx.x << 7;
  const int n = r0 >> 10, hw0 = r0 & 1023;
  const float* zbase = z + (size_t)n * 262144 + hw0;

  if (t < 128) a_l[t] = aws[r0 + t];

  const int dsub = t >> 5;         // 0..7
  const int rq4 = (t & 31) << 2;   // 0..124

  float minv[8];
  int mini[8];
#pragma unroll
  for (int i = 0; i < 8; ++i) {
    minv[i] = 3.4028235e38f;
    mini[i] = 0;
  }

  for (int kt = 0; kt < 8; ++kt) {
    const int kbase = kt << 7;
    float acc[8][8];
#pragma unroll
    for (int i = 0; i < 8; ++i)
#pragma unroll
      for (int j = 0; j < 8; ++j) acc[i][j] = 0.0f;

    if (t < 32) *(float4*)&c_l[t << 2] = *(const float4*)&cws[kbase + (t << 2)];

    // stage chunk 0
    float4 xv0 = *(const float4*)&zbase[(size_t)dsub * 1024 + rq4];
    float4 xv1 = *(const float4*)&zbase[(size_t)(dsub + 8) * 1024 + rq4];
    float4 ev0 = *(const float4*)&ET[(size_t)dsub * 1024 + kbase + rq4];
    float4 ev1 = *(const float4*)&ET[(size_t)(dsub + 8) * 1024 + kbase + rq4];
    *(float4*)&Xb[0][dsub * 128 + rq4] = xv0;
    *(float4*)&Xb[0][(dsub + 8) * 128 + rq4] = xv1;
    *(float4*)&Eb[0][dsub * 128 + rq4] = ev0;
    *(float4*)&Eb[0][(dsub + 8) * 128 + rq4] = ev1;
    __syncthreads();

    int cur = 0;
    for (int ch = 0; ch < 16; ++ch) {
      if (ch < 15) {
        const int dch = (ch + 1) << 4;
        xv0 = *(const float4*)&zbase[(size_t)(dch + dsub) * 1024 + rq4];
        xv1 = *(const float4*)&zbase[(size_t)(dch + dsub + 8) * 1024 + rq4];
        ev0 = *(const float4*)&ET[(size_t)(dch + dsub) * 1024 + kbase + rq4];
        ev1 = *(const float4*)&ET[(size_t)(dch + dsub + 8) * 1024 + kbase + rq4];
      }
      const float* Xc = Xb[cur];
      const float* Ec = Eb[cur];
#pragma unroll
      for (int d = 0; d < 16; ++d) {
        const float4 xa = *(const float4*)&Xc[d * 128 + (ty << 2)];
        const float4 xb = *(const float4*)&Xc[d * 128 + 64 + (ty << 2)];
        const float4 ea = *(const float4*)&Ec[d * 128 + (tx << 2)];
        const float4 eb = *(const float4*)&Ec[d * 128 + 64 + (tx << 2)];
        const float xr[8] = {xa.x, xa.y, xa.z, xa.w, xb.x, xb.y, xb.z, xb.w};
        const float er[8] = {ea.x, ea.y, ea.z, ea.w, eb.x, eb.y, eb.z, eb.w};
#pragma unroll
        for (int i = 0; i < 8; ++i)
#pragma unroll
          for (int j = 0; j < 8; ++j)
            acc[i][j] = fmaf(xr[i], er[j], acc[i][j]);
      }
      if (ch < 15) {
        const int nxt = cur ^ 1;
        *(float4*)&Xb[nxt][dsub * 128 + rq4] = xv0;
        *(float4*)&Xb[nxt][(dsub + 8) * 128 + rq4] = xv1;
        *(float4*)&Eb[nxt][dsub * 128 + rq4] = ev0;
        *(float4*)&Eb[nxt][(dsub + 8) * 128 + rq4] = ev1;
        __syncthreads();
        cur = nxt;
      }
    }

    // epilogue: quantized distance + running argmin (ascending k, strict <)
#pragma unroll
    for (int i = 0; i < 8; ++i) {
      const int rl = (i < 4) ? ((ty << 2) + i) : (64 + (ty << 2) + i - 4);
      const float av = a_l[rl];
#pragma unroll
      for (int j = 0; j < 8; ++j) {
        const int kl = (j < 4) ? ((tx << 2) + j) : (64 + (tx << 2) + j - 4);
        float s = fmaf(-2.0f, acc[i][j], av);  // fl(a - 2*dot), single rounding
        s = s + c_l[kl];                       // fl(s + c)
        if (s < minv[i]) {
          minv[i] = s;
          mini[i] = kbase + kl;
        }
      }
    }
    __syncthreads();
  }

  // cross-thread reduction: 16 tx-threads share each row
  float* rv = Xb[0];
  int* ri = (int*)Eb[0];
#pragma unroll
  for (int i = 0; i < 8; ++i) {
    const int rl = (i < 4) ? ((ty << 2) + i) : (64 + (ty << 2) + i - 4);
    rv[tx * 128 + rl] = minv[i];
    ri[tx * 128 + rl] = mini[i];
  }
  __syncthreads();
  if (t < 128) {
    float bv = rv[t];
    int bi = ri[t];
#pragma unroll
    for (int x = 1; x < 16; ++x) {
      const float v = rv[x * 128 + t];
      const int ii = ri[x * 128 + t];
      if (v < bv || (v == bv && ii < bi)) {
        bv = v;
        bi = ii;
      }
    }
    idxws[r0 + t] = bi;
    out[OUT_IDX_OFF + r0 + t] = (float)bi;
  }
}

// ---------------------------------------------------------------------------
// Kernel 3: z_q gather via LDS transpose (coalesced emb reads + NCHW writes),
// indices already written; accumulate vq_loss = 1.02 * mean((z - z_q)^2).
// ---------------------------------------------------------------------------
__global__ __launch_bounds__(256) void k_out(const float* __restrict__ z,
                                             const float* __restrict__ emb,
                                             const int* __restrict__ idxws,
                                             float* __restrict__ out) {
  __shared__ float zq[32][257];
  __shared__ int sidx[32];
  __shared__ float red[256];
  const int t = threadIdx.x;
  const int p0 = blockIdx.x << 5;
  const int n = p0 >> 10, hw0 = p0 & 1023;
  if (t < 32) sidx[t] = idxws[p0 + t];
  __syncthreads();
#pragma unroll
  for (int it = 0; it < 8; ++it) {
    const int i = t + (it << 8);
    const int p = i >> 6;
    const int q = (i & 63) << 2;
    const float4 v = *(const float4*)&emb[(size_t)sidx[p] * 256 + q];
    zq[p][q] = v.x;
    zq[p][q + 1] = v.y;
    zq[p][q + 2] = v.z;
    zq[p][q + 3] = v.w;
  }
  __syncthreads();
  const int p = t & 31, d0 = t >> 5;
  const float* zb = z + (size_t)n * 262144 + hw0 + p;
  float* ob = out + (size_t)n * 262144 + hw0 + p;
  float lacc = 0.0f;
#pragma unroll
  for (int dd = 0; dd < 32; ++dd) {
    const int d = (dd << 3) + d0;
    const float v = zq[p][d];
    const float zv = zb[(size_t)d * 1024];
    ob[(size_t)d * 1024] = v;
    const float df = zv - v;
    lacc = fmaf(df, df, lacc);
  }
  red[t] = lacc;
  __syncthreads();
  for (int s = 128; s > 0; s >>= 1) {
    if (t < s) red[t] += red[t + s];
    __syncthreads();
  }
  if (t == 0) atomicAdd(&out[OUT_LOSS_OFF], red[0] * (1.02f / 16777216.0f));
}

// ---------------------------------------------------------------------------
extern "C" void kernel_launch(void* const* d_in, const int* in_sizes, int n_in,
                              void* d_out, int out_size, void* d_ws,
                              size_t ws_size, hipStream_t stream) {
  const float* z = (const float*)d_in[0];
  const float* emb = (const float*)d_in[1];
  float* out = (float*)d_out;

  // workspace layout (floats): ET[262144] | c[1024] | a[65536] | idx[65536]
  float* ET = (float*)d_ws;
  float* cws = ET + 262144;
  float* aws = cws + 1024;
  int* idxws = (int*)(aws + 65536);

  hipMemsetAsync((char*)d_out + (size_t)OUT_LOSS_OFF * 4, 0, 4, stream);

  k_prep<<<dim3(1024), dim3(256), 0, stream>>>(emb, ET, cws);
  k_a<<<dim3(512), dim3(256), 0, stream>>>(z, aws);
  k_gemm<<<dim3(512), dim3(256), 0, stream>>>(z, ET, cws, aws, idxws, out);
  k_out<<<dim3(2048), dim3(256), 0, stream>>>(z, emb, idxws, out);
}

// Round 3
// 550.326 us; speedup vs baseline: 4.4835x; 1.2851x over previous
//
#include <hip/hip_runtime.h>
#include <hip/hip_bf16.h>
#include <float.h>

// z: (64, 256, 32, 32) fp32 ; emb: (1024, 256) fp32
// M = 65536 pixels, D = 256, K = 1024 codes
// out: [z_q (16777216 f)] [indices as float (65536)] [vq_loss (1)]
#define OUT_IDX_OFF 16777216
#define OUT_LOSS_OFF 16842752

typedef __attribute__((ext_vector_type(8))) short short8;
typedef __attribute__((ext_vector_type(4))) float f32x4;

static __device__ __forceinline__ unsigned short f2bf(float f) {
  union { __hip_bfloat16 h; unsigned short u; } cv;
  cv.h = __float2bfloat16(f);
  return cv.u;
}

// ---------------------------------------------------------------------------
// P1: emb -> E2 bf16 [1024 codes][256 k] + exact cws (unchanged tree reduce,
// proven in rounds 1-2).
// ---------------------------------------------------------------------------
__global__ __launch_bounds__(256) void k_prep(const float* __restrict__ emb,
                                              unsigned short* __restrict__ E2,
                                              float* __restrict__ cws) {
  const int k = blockIdx.x, d = threadIdx.x;
  const float v = emb[k * 256 + d];
  __shared__ float red[256];
  __shared__ unsigned short row[256];
  row[d] = f2bf(v);
  red[d] = v * v;
  __syncthreads();
  for (int s = 128; s > 0; s >>= 1) {
    if (d < s) red[d] += red[d + s];
    __syncthreads();
  }
  if (d == 0) cws[k] = red[0];
  if (d < 32) ((short8*)&E2[k * 256])[d] = ((short8*)row)[d];
}

// ---------------------------------------------------------------------------
// P2: z (NCHW) -> A2 bf16 [pixel][256] via LDS transpose. A2 lives in d_out's
// z_q region (scratch until k_out overwrites it).
// ---------------------------------------------------------------------------
__global__ __launch_bounds__(256) void k_cvt(const float* __restrict__ z,
                                             unsigned short* __restrict__ A2) {
  __shared__ float tile[32][258];
  const int t = threadIdx.x;
  const int p0 = blockIdx.x << 5;  // 32 pixels
  const int n = p0 >> 10, hw0 = p0 & 1023;
  const float* zb = z + (size_t)n * 262144 + hw0 + (t & 31);
  const int dh = t >> 5;  // 0..7
#pragma unroll
  for (int dd = 0; dd < 32; ++dd) {
    const int d = dd * 8 + dh;
    tile[t & 31][d] = zb[(size_t)d * 1024];
  }
  __syncthreads();
  const int p = t >> 3;            // pixel 0..31
  const int c0 = (t & 7) * 4;      // short8 chunk base
  unsigned short tmp[32];
#pragma unroll
  for (int j = 0; j < 32; ++j) tmp[j] = f2bf(tile[p][(t & 7) * 32 + j]);
  short8* dst = (short8*)&A2[(size_t)(p0 + p) * 256];
#pragma unroll
  for (int j = 0; j < 4; ++j) dst[c0 + j] = ((short8*)tmp)[j];
}

// ---------------------------------------------------------------------------
// k_a: exact numpy-pairwise ||x||^2 (unchanged, proven).
// ---------------------------------------------------------------------------
__global__ __launch_bounds__(256) void k_a(const float* __restrict__ z,
                                           float* __restrict__ aws) {
#pragma clang fp contract(off)
  const int t = threadIdx.x;
  const int r = (blockIdx.x << 7) + (t & 127);
  const int h = t >> 7;
  const int n = r >> 10;
  const int hw = r & 1023;
  const float* zp = z + (size_t)n * 262144 + hw + (size_t)h * 131072;
  float acc[8];
#pragma unroll
  for (int j = 0; j < 8; ++j) {
    const float x = zp[(size_t)j * 1024];
    acc[j] = x * x;
  }
  for (int g = 1; g < 16; ++g) {
#pragma unroll
    for (int j = 0; j < 8; ++j) {
      const float x = zp[(size_t)(g * 8 + j) * 1024];
      const float p = x * x;
      acc[j] = acc[j] + p;
    }
  }
  const float s = ((acc[0] + acc[1]) + (acc[2] + acc[3])) +
                  ((acc[4] + acc[5]) + (acc[6] + acc[7]));
  __shared__ float red[256];
  red[t] = s;
  __syncthreads();
  if (t < 128) aws[(blockIdx.x << 7) + t] = red[t] + red[t + 128];
}

// ---------------------------------------------------------------------------
// G: bf16 MFMA prefilter GEMM-argmin + exact fp32 rescore.
// Block = 128 pixels x 1024 codes. A2 tile resident in LDS (read once); B
// chunks (128 codes x 256 k) streamed with register prefetch. 4 waves in 2x2,
// each 64x64 via 4x4 grid of 16x16x32 MFMA tiles, acc 64 VGPR.
// Approx score t = c_k - 2*dot_bf16 (err rms ~5e-5); candidates within
// DELTA=2e-3 of running row min; exact rescore = round-1 arithmetic
// (ascending-d fmaf chain) -> provably identical indices to round 2.
// LDS 149.5 KB -> 1 block/CU.
// ---------------------------------------------------------------------------
#define G_SMEM 149504
__global__ __launch_bounds__(256, 1) void k_mfma(
    const unsigned short* __restrict__ A2, const unsigned short* __restrict__ E2,
    const float* __restrict__ cws, const float* __restrict__ aws,
    const float* __restrict__ z, const float* __restrict__ emb,
    int* __restrict__ idxws, float* __restrict__ out) {
  extern __shared__ __align__(16) char smem[];
  unsigned short* As = (unsigned short*)smem;   // 128 x 264 (pad 8 shorts)
  unsigned short* Bs = As + 128 * 264;          // 128 x 264
  float* c_l = (float*)(Bs + 128 * 264);        // 1024
  float* rowmin = c_l + 1024;                   // 128
  float* rmkt = rowmin + 128;                   // 128 x 2
  int* cnt = (int*)(rmkt + 256);                // 128
  int* cand = cnt + 128;                        // 128 x 16

  const int t = threadIdx.x;
  const int lane = t & 63, wave = t >> 6;
  const int wr = wave >> 1, wc = wave & 1;
  const int quad = lane >> 4, l15 = lane & 15;
  const int r0 = blockIdx.x << 7;

  ((float4*)c_l)[t] = ((const float4*)cws)[t];
  if (t < 128) { rowmin[t] = FLT_MAX; cnt[t] = 0; }

  // stage A (once per block; global read of A2 happens exactly once total)
  {
    const short8* gA = (const short8*)(A2 + (size_t)r0 * 256);
    short8 v[16];
#pragma unroll
    for (int i = 0; i < 16; ++i) v[i] = gA[i * 256 + t];
#pragma unroll
    for (int i = 0; i < 16; ++i) {
      const int row = i * 8 + (t >> 5), ch = t & 31;
      *(short8*)&As[row * 264 + ch * 8] = v[i];
    }
  }
  // stage B chunk 0
  {
    const short8* gB = (const short8*)E2;
    short8 v[16];
#pragma unroll
    for (int i = 0; i < 16; ++i) v[i] = gB[i * 256 + t];
#pragma unroll
    for (int i = 0; i < 16; ++i) {
      const int row = i * 8 + (t >> 5), ch = t & 31;
      *(short8*)&Bs[row * 264 + ch * 8] = v[i];
    }
  }
  __syncthreads();

  short8 pref[16];
  for (int kt = 0; kt < 8; ++kt) {
    if (kt < 7) {  // prefetch next B chunk; loads fly during compute
      const short8* gB = (const short8*)(E2 + (size_t)(kt + 1) * 128 * 256);
#pragma unroll
      for (int i = 0; i < 16; ++i) pref[i] = gB[i * 256 + t];
    }
    f32x4 acc[4][4];
#pragma unroll
    for (int a = 0; a < 4; ++a)
#pragma unroll
      for (int b = 0; b < 4; ++b) acc[a][b] = (f32x4)(0.0f);

#pragma unroll
    for (int ks = 0; ks < 8; ++ks) {
      short8 af[4], bf[4];
#pragma unroll
      for (int tr = 0; tr < 4; ++tr)
        af[tr] = *(const short8*)&As[(wr * 64 + tr * 16 + l15) * 264 + ks * 32 + quad * 8];
#pragma unroll
      for (int tc = 0; tc < 4; ++tc)
        bf[tc] = *(const short8*)&Bs[(wc * 64 + tc * 16 + l15) * 264 + ks * 32 + quad * 8];
#pragma unroll
      for (int tr = 0; tr < 4; ++tr)
#pragma unroll
        for (int tc = 0; tc < 4; ++tc)
          acc[tr][tc] = __builtin_amdgcn_mfma_f32_16x16x32_bf16(
              af[tr], bf[tc], acc[tr][tc], 0, 0, 0);
    }

    // epilogue phase 1: this chunk's per-row min
#pragma unroll
    for (int tr = 0; tr < 4; ++tr)
#pragma unroll
      for (int rg = 0; rg < 4; ++rg) {
        const int rloc = wr * 64 + tr * 16 + quad * 4 + rg;
        float mn = FLT_MAX;
#pragma unroll
        for (int tc = 0; tc < 4; ++tc) {
          const int nl = wc * 64 + tc * 16 + l15;
          const float s = fmaf(-2.0f, acc[tr][tc][rg], c_l[kt * 128 + nl]);
          mn = fminf(mn, s);
        }
        mn = fminf(mn, __shfl_xor(mn, 1));
        mn = fminf(mn, __shfl_xor(mn, 2));
        mn = fminf(mn, __shfl_xor(mn, 4));
        mn = fminf(mn, __shfl_xor(mn, 8));
        if (l15 == 0) rmkt[rloc * 2 + wc] = mn;
      }
    __syncthreads();  // compute reads of Bs done; rmkt visible
    if (t < 128) rowmin[t] = fminf(rowmin[t], fminf(rmkt[t * 2], rmkt[t * 2 + 1]));
    if (kt < 7) {
#pragma unroll
      for (int i = 0; i < 16; ++i) {
        const int row = i * 8 + (t >> 5), ch = t & 31;
        *(short8*)&Bs[row * 264 + ch * 8] = pref[i];
      }
    }
    __syncthreads();  // rowmin + new B visible
    // candidate append vs running min (acc regs still live)
#pragma unroll
    for (int tr = 0; tr < 4; ++tr)
#pragma unroll
      for (int rg = 0; rg < 4; ++rg) {
        const int rloc = wr * 64 + tr * 16 + quad * 4 + rg;
        const float lim = rowmin[rloc] + 2.0e-3f;
#pragma unroll
        for (int tc = 0; tc < 4; ++tc) {
          const int nl = wc * 64 + tc * 16 + l15;
          const float s = fmaf(-2.0f, acc[tr][tc][rg], c_l[kt * 128 + nl]);
          if (s <= lim) {
            const int pos = atomicAdd(&cnt[rloc], 1);
            if (pos < 16) cand[rloc * 16 + pos] = kt * 128 + nl;
          }
        }
      }
  }
  __syncthreads();

  // exact rescore: round-1 arithmetic, bit-identical scores -> same indices
  if (t < 128) {
    const int r = r0 + t;
    const int n = r >> 10, hw = r & 1023;
    const float* zp = z + (size_t)n * 262144 + hw;
    const float a = aws[r];
    int m = cnt[t];
    if (m > 16) m = 16;
    float bestv = FLT_MAX;
    int besti = 0x7fffffff;
    for (int ci = 0; ci < m; ++ci) {
      const int k = cand[t * 16 + ci];
      const float* ep = emb + (size_t)k * 256;
      float dot = 0.0f;
#pragma unroll 8
      for (int d = 0; d < 256; ++d) dot = fmaf(zp[(size_t)d * 1024], ep[d], dot);
      float s = fmaf(-2.0f, dot, a);  // fl(a - 2*dot)
      s = s + c_l[k];                 // fl(s + c)
      if (s < bestv || (s == bestv && k < besti)) { bestv = s; besti = k; }
    }
    idxws[r] = besti;
    out[OUT_IDX_OFF + r] = (float)besti;
  }
}

// ---------------------------------------------------------------------------
// k_out: z_q gather + loss (unchanged, proven). Overwrites the A2 scratch
// region of d_out with the real z_q.
// ---------------------------------------------------------------------------
__global__ __launch_bounds__(256) void k_out(const float* __restrict__ z,
                                             const float* __restrict__ emb,
                                             const int* __restrict__ idxws,
                                             float* __restrict__ out) {
  __shared__ float zq[32][257];
  __shared__ int sidx[32];
  __shared__ float red[256];
  const int t = threadIdx.x;
  const int p0 = blockIdx.x << 5;
  const int n = p0 >> 10, hw0 = p0 & 1023;
  if (t < 32) sidx[t] = idxws[p0 + t];
  __syncthreads();
#pragma unroll
  for (int it = 0; it < 8; ++it) {
    const int i = t + (it << 8);
    const int p = i >> 6;
    const int q = (i & 63) << 2;
    const float4 v = *(const float4*)&emb[(size_t)sidx[p] * 256 + q];
    zq[p][q] = v.x;
    zq[p][q + 1] = v.y;
    zq[p][q + 2] = v.z;
    zq[p][q + 3] = v.w;
  }
  __syncthreads();
  const int p = t & 31, d0 = t >> 5;
  const float* zb = z + (size_t)n * 262144 + hw0 + p;
  float* ob = out + (size_t)n * 262144 + hw0 + p;
  float lacc = 0.0f;
#pragma unroll
  for (int dd = 0; dd < 32; ++dd) {
    const int d = (dd << 3) + d0;
    const float v = zq[p][d];
    const float zv = zb[(size_t)d * 1024];
    ob[(size_t)d * 1024] = v;
    const float df = zv - v;
    lacc = fmaf(df, df, lacc);
  }
  red[t] = lacc;
  __syncthreads();
  for (int s = 128; s > 0; s >>= 1) {
    if (t < s) red[t] += red[t + s];
    __syncthreads();
  }
  if (t == 0) atomicAdd(&out[OUT_LOSS_OFF], red[0] * (1.02f / 16777216.0f));
}

// ---------------------------------------------------------------------------
extern "C" void kernel_launch(void* const* d_in, const int* in_sizes, int n_in,
                              void* d_out, int out_size, void* d_ws,
                              size_t ws_size, hipStream_t stream) {
  const float* z = (const float*)d_in[0];
  const float* emb = (const float*)d_in[1];
  float* out = (float*)d_out;

  // ws layout: E2 bf16 [1024*256] | cws [1024] | aws [65536] | idx [65536]
  unsigned short* E2 = (unsigned short*)d_ws;
  float* cws = (float*)(E2 + 262144);
  float* aws = cws + 1024;
  int* idxws = (int*)(aws + 65536);
  // A2 bf16 (33.5 MB) lives in d_out's z_q region; k_out overwrites it last.
  unsigned short* A2 = (unsigned short*)d_out;

  hipFuncSetAttribute((const void*)k_mfma,
                      hipFuncAttributeMaxDynamicSharedMemorySize, G_SMEM);
  hipMemsetAsync((char*)d_out + (size_t)OUT_LOSS_OFF * 4, 0, 4, stream);

  k_prep<<<dim3(1024), dim3(256), 0, stream>>>(emb, E2, cws);
  k_cvt<<<dim3(2048), dim3(256), 0, stream>>>(z, A2);
  k_a<<<dim3(512), dim3(256), 0, stream>>>(z, aws);
  k_mfma<<<dim3(512), dim3(256), G_SMEM, stream>>>(A2, E2, cws, aws, z, emb,
                                                   idxws, out);
  k_out<<<dim3(2048), dim3(256), 0, stream>>>(z, emb, idxws, out);
}